// Round 9
// baseline (568.796 us; speedup 1.0000x reference)
//
#include <hip/hip_runtime.h>
#include <hip/hip_bf16.h>
#include <math.h>

#define EPSC 1e-5f

typedef __attribute__((ext_vector_type(8))) short bf16x8;
typedef __attribute__((ext_vector_type(4))) float f32x4;
typedef __attribute__((ext_vector_type(8))) unsigned short u16x8;

constexpr int Bn = 16, Cn = 96, Hn = 112, Wn = 112, HWn = Hn * Wn; // 12544
constexpr int NT = 64, TPI = HWn / NT;                             // 196

#define MFMA16(a, b, c) __builtin_amdgcn_mfma_f32_16x16x32_bf16((a), (b), (c), 0, 0, 0)

__device__ __forceinline__ ushort f2bf(float f) {
    __hip_bfloat16 h = __float2bfloat16(f);
    return __builtin_bit_cast(ushort, h);
}
__device__ __forceinline__ float bf2f(ushort u) {
    return __builtin_bit_cast(float, (unsigned)u << 16);
}
// tanh-form GELU: x * sigmoid(1.5957691*x + 0.0713548*x^3); |err| <= ~3e-4
__device__ __forceinline__ float gelu_f(float x) {
    float t = x * x;
    float z = x * fmaf(0.0713548162726f, t, 1.59576912161f);
    float e = __expf(-z);
    return __fdividef(x, 1.0f + e);
}
__device__ __forceinline__ uint pk2(float lo, float hi) {
    return (uint)f2bf(lo) | ((uint)f2bf(hi) << 16);
}

// ---------------- BN folding ----------------
// prm: A1[0:96] B1[96:192] Ag[192:384] Bg[384:576] A2[576:672] B2[672:768]
__global__ __launch_bounds__(256) void params_kernel(
    const float* __restrict__ b1, const float* __restrict__ g1, const float* __restrict__ be1,
    const float* __restrict__ m1, const float* __restrict__ v1,
    const float* __restrict__ bg, const float* __restrict__ gg, const float* __restrict__ beg,
    const float* __restrict__ mg, const float* __restrict__ vg,
    const float* __restrict__ b2, const float* __restrict__ g2, const float* __restrict__ be2,
    const float* __restrict__ m2, const float* __restrict__ v2,
    float* __restrict__ P)
{
    int t = threadIdx.x;
    if (t < 96) {
        float s = g1[t] * rsqrtf(v1[t] + EPSC);
        P[t]       = s;
        P[96 + t]  = (b1[t] - m1[t]) * s + be1[t];
        float s2 = g2[t] * rsqrtf(v2[t] + EPSC);
        P[576 + t] = s2;
        P[672 + t] = (b2[t] - m2[t]) * s2 + be2[t];
    }
    if (t < 192) {
        float s = gg[t] * rsqrtf(vg[t] + EPSC);
        P[192 + t] = s;
        P[384 + t] = (bg[t] - mg[t]) * s + beg[t];
    }
}

// ---------------- weight pack ----------------
// standard (w1, wg, wf1): element (mt,kc,lane,e) = W[mt*16 + lane%16][kc*32 + (lane>>4)*8 + e]
// permuted (w2, wf2):     k-col slot carries the producer's D-register channel
//   T = ((kc>>1)*4 + (kc&1)*2 + (e>>2))*16 + (lane>>4)*4 + (e&3)
// so a producer GEMM's D registers feed the consumer's B-frag with zero shuffles.
__global__ __launch_bounds__(256) void pack_kernel(
    const float* __restrict__ w1, const float* __restrict__ wg, const float* __restrict__ w2,
    const float* __restrict__ wf1, const float* __restrict__ wf2,
    ushort* __restrict__ dst)
{
    int idx = blockIdx.x * 256 + threadIdx.x;
    if (idx >= 138240) return;
    const float* src; int K, off; bool perm;
    if      (idx <   9216) { src = w1;  K =  96; off = 0;      perm = false; }
    else if (idx <  46080) { src = wg;  K = 192; off = 9216;   perm = false; }
    else if (idx <  64512) { src = w2;  K = 192; off = 46080;  perm = true;  }
    else if (idx < 101376) { src = wf1; K =  96; off = 64512;  perm = false; }
    else                   { src = wf2; K = 384; off = 101376; perm = true;  }
    int r = idx - off;
    int e = r & 7, lane = (r >> 3) & 63, tile = r >> 9;
    int KC = K / 32;
    int kc = tile % KC, mt = tile / KC;
    int row = mt * 16 + (lane & 15);
    int col;
    if (!perm) col = kc * 32 + (lane >> 4) * 8 + e;
    else       col = ((kc >> 1) * 4 + (kc & 1) * 2 + (e >> 2)) * 16 + (lane >> 4) * 4 + (e & 3);
    dst[idx] = f2bf(src[(size_t)row * K + col]);
}

// ---------------- parity mins ----------------
__global__ __launch_bounds__(256) void mins_kernel(
    const ushort* __restrict__ h, float* __restrict__ rmin2, float* __restrict__ cmin2)
{
    __shared__ __align__(16) ushort sl[112 * 96];
    int bid = blockIdx.x;            // Bn * 2 * 112
    int b = bid / 224, rem = bid % 224, mode = rem / 112, line = rem % 112;
    int t = threadIdx.x;
    if (mode == 0) {
        const ushort* base = h + ((size_t)b * HWn + line * Wn) * Cn;
        for (int v = t; v < 1344; v += 256)
            *(u16x8*)&sl[v * 8] = *(const u16x8*)&base[v * 8];
    } else {
        for (int v = t; v < 1344; v += 256) {
            int i = v / 12, g = v % 12;
            *(u16x8*)&sl[(i * 12 + g) * 8] =
                *(const u16x8*)&h[((size_t)b * HWn + i * Wn + line) * Cn + g * 8];
        }
    }
    __syncthreads();
    if (t < 192) {
        int c = t % 96, p = t / 96;
        float m = 1e30f;
        #pragma unroll 8
        for (int n = 0; n < 56; ++n) m = fminf(m, bf2f(sl[(p + 2 * n) * 96 + c]));
        float* dst = (mode == 0) ? rmin2 : cmin2;
        dst[(((size_t)b * 112 + line) * 2 + p) * 96 + c] = m;
    }
}

// ---------------- fc1: h = BN(W1 x) -> bf16 [b][hw][96] ----------------
__global__ __launch_bounds__(256) void fc1_kernel(
    const float* __restrict__ X, const ushort* __restrict__ w1p,
    const float* __restrict__ prm, ushort* __restrict__ hbuf)
{
    __shared__ __align__(16) ushort Hs[64 * 104];
    int bid = blockIdx.x, b = bid / TPI, hw0 = (bid % TPI) * NT;
    int t = threadIdx.x, lane = t & 63, wave = t >> 6;
    int wm = wave >> 1, wn = wave & 1, q = lane >> 4, sl = lane & 15;

    bf16x8 bfr[3][2];
    #pragma unroll
    for (int kc = 0; kc < 3; ++kc)
        #pragma unroll
        for (int nc = 0; nc < 2; ++nc) {
            int s = hw0 + wn * 32 + nc * 16 + sl;
            union { bf16x8 v; ushort u[8]; } f;
            #pragma unroll
            for (int e = 0; e < 8; ++e) {
                int c = kc * 32 + q * 8 + e;
                f.u[e] = f2bf(X[((size_t)b * Cn + c) * HWn + s]);
            }
            bfr[kc][nc] = f.v;
        }
    f32x4 acc[3][2] = {};
    #pragma unroll
    for (int kc = 0; kc < 3; ++kc)
        #pragma unroll
        for (int m = 0; m < 3; ++m) {
            bf16x8 af = *(const bf16x8*)&w1p[(((wm * 3 + m) * 3 + kc) * 64 + lane) * 8];
            acc[m][0] = MFMA16(af, bfr[kc][0], acc[m][0]);
            acc[m][1] = MFMA16(af, bfr[kc][1], acc[m][1]);
        }
    #pragma unroll
    for (int m = 0; m < 3; ++m) {
        int o0 = (wm * 3 + m) * 16 + q * 4;
        f32x4 a4 = *(const f32x4*)&prm[o0];
        f32x4 s4 = *(const f32x4*)&prm[96 + o0];
        #pragma unroll
        for (int nc = 0; nc < 2; ++nc) {
            int srow = wn * 32 + nc * 16 + sl;
            ushort4 pk;
            pk.x = f2bf(acc[m][nc][0] * a4[0] + s4[0]);
            pk.y = f2bf(acc[m][nc][1] * a4[1] + s4[1]);
            pk.z = f2bf(acc[m][nc][2] * a4[2] + s4[2]);
            pk.w = f2bf(acc[m][nc][3] * a4[3] + s4[3]);
            *(ushort4*)&Hs[srow * 104 + o0] = pk;
        }
    }
    __syncthreads();
    for (int v = t; v < 768; v += 256) {
        int s = v / 12, g = v % 12;
        *(u16x8*)&hbuf[((size_t)b * HWn + hw0 + s) * Cn + g * 8] = *(const u16x8*)&Hs[s * 104 + g * 8];
    }
}

// ---------------- grapher v9: cat(LDS) -> [fcg 2mt -> fc2 partial] -> reduce -> +res ----------------
// wm splits fcg M (weight traffic as r5); fc2 accumulated partially per wave via
// permuted w2p; ONE cross-wave reduce at the end. 3 barriers, no g round trip.
__global__ __launch_bounds__(256) void grapher_kernel(
    const ushort* __restrict__ hbuf, const float* __restrict__ Xres,
    const ushort* __restrict__ wgp, const ushort* __restrict__ w2p,
    const float* __restrict__ prm,
    const float* __restrict__ cmin2, const float* __restrict__ rmin2,
    ushort* __restrict__ rbuf)
{
    __shared__ __align__(16) char smem[28672];       // max(cat 25.6KB, red 28.7KB)
    ushort* Xs = (ushort*)smem;                      // [64][200] cat tile
    float*  red = (float*)smem;                      // [4 waves][64 lanes][28]

    int bid = blockIdx.x, b = bid / TPI, hw0 = (bid % TPI) * NT;
    int t = threadIdx.x, lane = t & 63, wave = t >> 6;
    int wm = wave >> 1, wn = wave & 1, q = lane >> 4, sl = lane & 15;

    // ---- stage cat tile (coalesced) ----
    for (int v = t; v < 768; v += 256) {
        int s = v / 12, g = v % 12;
        u16x8 hv = *(const u16x8*)&hbuf[((size_t)b * HWn + hw0 + s) * Cn + g * 8];
        *(u16x8*)&Xs[s * 200 + g * 8] = hv;
        int pos = hw0 + s, i = pos / Wn, j = pos - i * Wn;
        const float* cm = &cmin2[(((size_t)b * 112 + j) * 2 + (i & 1)) * 96 + g * 8];
        const float* rm = &rmin2[(((size_t)b * 112 + i) * 2 + (j & 1)) * 96 + g * 8];
        union { u16x8 v; ushort u[8]; } hh, xx;
        hh.v = hv;
        #pragma unroll
        for (int e = 0; e < 8; ++e) {
            float hf = bf2f(hh.u[e]);
            xx.u[e] = f2bf(fmaxf(hf - cm[e], hf - rm[e]));   // mins include self => >= 0
        }
        *(u16x8*)&Xs[s * 200 + 96 + g * 8] = xx.v;
    }
    __syncthreads();                                  // bar1

    // ---- hoist cat B-frags ----
    bf16x8 cb[6][2];
    #pragma unroll
    for (int kc = 0; kc < 6; ++kc)
        #pragma unroll
        for (int n = 0; n < 2; ++n)
            cb[kc][n] = *(const bf16x8*)&Xs[(wn * 32 + n * 16 + sl) * 200 + kc * 32 + q * 8];

    // ---- 3 chunks: fcg (2 mt) -> gelu+pack -> fc2 partial ----
    f32x4 r2[6][2] = {};
    #pragma unroll
    for (int cc = 0; cc < 3; ++cc) {
        const int mt0 = wm * 6 + 2 * cc;
        f32x4 ga[2][2] = {};
        #pragma unroll
        for (int kc = 0; kc < 6; ++kc) {
            bf16x8 af0 = *(const bf16x8*)&wgp[(((mt0 + 0) * 6 + kc) * 64 + lane) * 8];
            bf16x8 af1 = *(const bf16x8*)&wgp[(((mt0 + 1) * 6 + kc) * 64 + lane) * 8];
            ga[0][0] = MFMA16(af0, cb[kc][0], ga[0][0]);
            ga[0][1] = MFMA16(af0, cb[kc][1], ga[0][1]);
            ga[1][0] = MFMA16(af1, cb[kc][0], ga[1][0]);
            ga[1][1] = MFMA16(af1, cb[kc][1], ga[1][1]);
        }
        uint gpk[2][2][2];
        #pragma unroll
        for (int mi = 0; mi < 2; ++mi) {
            int t0 = (mt0 + mi) * 16 + q * 4;
            f32x4 a4 = *(const f32x4*)&prm[192 + t0];
            f32x4 s4 = *(const f32x4*)&prm[384 + t0];
            #pragma unroll
            for (int n = 0; n < 2; ++n) {
                gpk[mi][n][0] = pk2(gelu_f(ga[mi][n][0] * a4[0] + s4[0]),
                                    gelu_f(ga[mi][n][1] * a4[1] + s4[1]));
                gpk[mi][n][1] = pk2(gelu_f(ga[mi][n][2] * a4[2] + s4[2]),
                                    gelu_f(ga[mi][n][3] * a4[3] + s4[3]));
            }
        }
        union { bf16x8 v; uint d[4]; } gb[2];
        #pragma unroll
        for (int n = 0; n < 2; ++n) {
            gb[n].d[0] = gpk[0][n][0]; gb[n].d[1] = gpk[0][n][1];
            gb[n].d[2] = gpk[1][n][0]; gb[n].d[3] = gpk[1][n][1];
        }
        const int kc2 = wm * 3 + cc;                  // M(kc2) == mt0 (verified)
        #pragma unroll
        for (int m = 0; m < 6; ++m) {
            bf16x8 af = *(const bf16x8*)&w2p[((m * 6 + kc2) * 64 + lane) * 8];
            r2[m][0] = MFMA16(af, gb[0].v, r2[m][0]);
            r2[m][1] = MFMA16(af, gb[1].v, r2[m][1]);
        }
    }

    __syncthreads();                                  // bar2: Xs reads done before red overwrite
    // ---- write complement m-half (constant indices per branch) ----
    {
        float* my = red + ((size_t)wave * 64 + lane) * 28;
        if (wm == 0) {
            #pragma unroll
            for (int mi = 0; mi < 3; ++mi)
                #pragma unroll
                for (int n = 0; n < 2; ++n)
                    *(f32x4*)&my[(mi * 2 + n) * 4] = r2[3 + mi][n];
        } else {
            #pragma unroll
            for (int mi = 0; mi < 3; ++mi)
                #pragma unroll
                for (int n = 0; n < 2; ++n)
                    *(f32x4*)&my[(mi * 2 + n) * 4] = r2[mi][n];
        }
    }
    __syncthreads();                                  // bar3
    // ---- read partner, add, BN + residual -> rbuf ----
    {
        const float* pr = red + ((size_t)(wave ^ 2) * 64 + lane) * 28;
        #pragma unroll
        for (int mi = 0; mi < 3; ++mi) {
            int m = wm * 3 + mi;
            int t0 = m * 16 + q * 4;
            f32x4 a4 = *(const f32x4*)&prm[576 + t0];
            f32x4 s4 = *(const f32x4*)&prm[672 + t0];
            #pragma unroll
            for (int n = 0; n < 2; ++n) {
                f32x4 part = *(const f32x4*)&pr[(mi * 2 + n) * 4];
                f32x4 own = (wm == 0) ? r2[mi][n] : r2[3 + mi][n];
                int s = hw0 + wn * 32 + n * 16 + sl;
                float rv[4];
                #pragma unroll
                for (int r = 0; r < 4; ++r)
                    rv[r] = (own[r] + part[r]) * a4[r] + s4[r]
                          + Xres[((size_t)b * 96 + t0 + r) * HWn + s];
                ushort4 pk;
                pk.x = f2bf(rv[0]); pk.y = f2bf(rv[1]); pk.z = f2bf(rv[2]); pk.w = f2bf(rv[3]);
                *(ushort4*)&rbuf[((size_t)b * HWn + s) * 96 + t0] = pk;
            }
        }
    }
}

// ---------------- ffn v9: stage r -> [ffn1 2mt -> gelu -> ffn2 partial] -> reduce ----------------
// wm splits mid M; ffn2 accumulated partially via permuted wf2p; one reduce.
__global__ __launch_bounds__(256) void ffn_kernel(
    const ushort* __restrict__ rbuf,
    const ushort* __restrict__ wf1p, const float* __restrict__ bf1,
    const ushort* __restrict__ wf2p, const float* __restrict__ bf2,
    float* __restrict__ Out)
{
    __shared__ __align__(16) char smem[28672];       // max(Rs 13.3KB, red 28.7KB)
    ushort* Rs  = (ushort*)smem;                     // [64][104]
    float*  red = (float*)smem;

    int bid = blockIdx.x, b = bid / TPI, hw0 = (bid % TPI) * NT;
    int t = threadIdx.x, lane = t & 63, wave = t >> 6;
    int wm = wave >> 1, wn = wave & 1, q = lane >> 4, sl = lane & 15;

    for (int v = t; v < 768; v += 256) {
        int s = v / 12, g = v % 12;
        *(u16x8*)&Rs[s * 104 + g * 8] = *(const u16x8*)&rbuf[((size_t)b * HWn + hw0 + s) * Cn + g * 8];
    }
    __syncthreads();                                  // bar1

    bf16x8 rb[3][2];
    #pragma unroll
    for (int kc = 0; kc < 3; ++kc)
        #pragma unroll
        for (int n = 0; n < 2; ++n)
            rb[kc][n] = *(const bf16x8*)&Rs[(wn * 32 + n * 16 + sl) * 104 + kc * 32 + q * 8];

    f32x4 oacc[6][2] = {};
    #pragma unroll
    for (int cc = 0; cc < 6; ++cc) {
        const int mt0 = wm * 12 + 2 * cc;
        f32x4 a1[2][2] = {};
        #pragma unroll
        for (int kc = 0; kc < 3; ++kc) {
            bf16x8 af0 = *(const bf16x8*)&wf1p[(((mt0 + 0) * 3 + kc) * 64 + lane) * 8];
            bf16x8 af1 = *(const bf16x8*)&wf1p[(((mt0 + 1) * 3 + kc) * 64 + lane) * 8];
            a1[0][0] = MFMA16(af0, rb[kc][0], a1[0][0]);
            a1[0][1] = MFMA16(af0, rb[kc][1], a1[0][1]);
            a1[1][0] = MFMA16(af1, rb[kc][0], a1[1][0]);
            a1[1][1] = MFMA16(af1, rb[kc][1], a1[1][1]);
        }
        uint mpk[2][2][2];
        #pragma unroll
        for (int mi = 0; mi < 2; ++mi) {
            f32x4 b4 = *(const f32x4*)&bf1[(mt0 + mi) * 16 + q * 4];
            #pragma unroll
            for (int n = 0; n < 2; ++n) {
                mpk[mi][n][0] = pk2(gelu_f(a1[mi][n][0] + b4[0]), gelu_f(a1[mi][n][1] + b4[1]));
                mpk[mi][n][1] = pk2(gelu_f(a1[mi][n][2] + b4[2]), gelu_f(a1[mi][n][3] + b4[3]));
            }
        }
        union { bf16x8 v; uint d[4]; } mB[2];
        #pragma unroll
        for (int n = 0; n < 2; ++n) {
            mB[n].d[0] = mpk[0][n][0]; mB[n].d[1] = mpk[0][n][1];
            mB[n].d[2] = mpk[1][n][0]; mB[n].d[3] = mpk[1][n][1];
        }
        const int kc2 = wm * 6 + cc;                  // M(kc2) == mt0 (verified)
        #pragma unroll
        for (int m = 0; m < 6; ++m) {
            bf16x8 af = *(const bf16x8*)&wf2p[((m * 12 + kc2) * 64 + lane) * 8];
            oacc[m][0] = MFMA16(af, mB[0].v, oacc[m][0]);
            oacc[m][1] = MFMA16(af, mB[1].v, oacc[m][1]);
        }
    }

    __syncthreads();                                  // bar2: Rs reads done before red overwrite
    {
        float* my = red + ((size_t)wave * 64 + lane) * 28;
        if (wm == 0) {
            #pragma unroll
            for (int mi = 0; mi < 3; ++mi)
                #pragma unroll
                for (int n = 0; n < 2; ++n)
                    *(f32x4*)&my[(mi * 2 + n) * 4] = oacc[3 + mi][n];
        } else {
            #pragma unroll
            for (int mi = 0; mi < 3; ++mi)
                #pragma unroll
                for (int n = 0; n < 2; ++n)
                    *(f32x4*)&my[(mi * 2 + n) * 4] = oacc[mi][n];
        }
    }
    __syncthreads();                                  // bar3
    {
        const float* pr = red + ((size_t)(wave ^ 2) * 64 + lane) * 28;
        #pragma unroll
        for (int mi = 0; mi < 3; ++mi) {
            int m = wm * 3 + mi;
            int t0 = m * 16 + q * 4;
            f32x4 b4 = *(const f32x4*)&bf2[t0];
            #pragma unroll
            for (int n = 0; n < 2; ++n) {
                f32x4 part = *(const f32x4*)&pr[(mi * 2 + n) * 4];
                f32x4 own = (wm == 0) ? oacc[mi][n] : oacc[3 + mi][n];
                int s = hw0 + wn * 32 + n * 16 + sl;
                #pragma unroll
                for (int r = 0; r < 4; ++r)
                    Out[((size_t)b * 96 + t0 + r) * HWn + s] = own[r] + part[r] + b4[r];
            }
        }
    }
}

extern "C" void kernel_launch(void* const* d_in, const int* in_sizes, int n_in,
                              void* d_out, int out_size, void* d_ws, size_t ws_size,
                              hipStream_t stream) {
    (void)in_sizes; (void)n_in; (void)out_size; (void)ws_size;
    const float* x   = (const float*)d_in[0];
    const float* w1  = (const float*)d_in[1];
    const float* b1  = (const float*)d_in[2];
    const float* g1  = (const float*)d_in[3];
    const float* be1 = (const float*)d_in[4];
    const float* m1  = (const float*)d_in[5];
    const float* v1  = (const float*)d_in[6];
    const float* wg  = (const float*)d_in[7];
    const float* bg  = (const float*)d_in[8];
    const float* gg  = (const float*)d_in[9];
    const float* beg = (const float*)d_in[10];
    const float* mg  = (const float*)d_in[11];
    const float* vg  = (const float*)d_in[12];
    const float* w2  = (const float*)d_in[13];
    const float* b2  = (const float*)d_in[14];
    const float* g2  = (const float*)d_in[15];
    const float* be2 = (const float*)d_in[16];
    const float* m2  = (const float*)d_in[17];
    const float* v2  = (const float*)d_in[18];
    const float* wf1 = (const float*)d_in[19];
    const float* bf1 = (const float*)d_in[20];
    const float* wf2 = (const float*)d_in[21];
    const float* bf2 = (const float*)d_in[22];
    float* out = (float*)d_out;

    char* base = (char*)d_ws;
    const size_t H_BYTES   = (size_t)Bn * HWn * Cn * 2;
    const size_t MIN_BYTES = (size_t)Bn * 112 * 2 * 96 * 4;
    ushort* hbuf  = (ushort*)base;                         // h, overwritten by r
    float*  rmin2 = (float*)(base + H_BYTES);
    float*  cmin2 = (float*)(base + H_BYTES + MIN_BYTES);
    float*  prm   = (float*)(base + H_BYTES + 2 * MIN_BYTES);
    ushort* wpack = (ushort*)(base + H_BYTES + 2 * MIN_BYTES + 3072);
    ushort* w1p  = wpack;
    ushort* wgp  = wpack + 9216;
    ushort* w2p  = wpack + 46080;
    ushort* wf1p = wpack + 64512;
    ushort* wf2p = wpack + 101376;

    params_kernel<<<dim3(1), dim3(256), 0, stream>>>(
        b1, g1, be1, m1, v1, bg, gg, beg, mg, vg, b2, g2, be2, m2, v2, prm);
    pack_kernel<<<dim3(540), dim3(256), 0, stream>>>(w1, wg, w2, wf1, wf2, wpack);

    dim3 blk(256);
    fc1_kernel<<<dim3(Bn * TPI), blk, 0, stream>>>(x, w1p, prm, hbuf);
    mins_kernel<<<dim3(Bn * 2 * 112), blk, 0, stream>>>(hbuf, rmin2, cmin2);
    grapher_kernel<<<dim3(Bn * TPI), blk, 0, stream>>>(hbuf, x, wgp, w2p,
                                                       prm, cmin2, rmin2, hbuf);
    ffn_kernel<<<dim3(Bn * TPI), blk, 0, stream>>>(hbuf, wf1p, bf1, wf2p, bf2, out);
}

// Round 10
// 311.849 us; speedup vs baseline: 1.8239x; 1.8239x over previous
//
#include <hip/hip_runtime.h>
#include <hip/hip_bf16.h>
#include <math.h>

#define EPSC 1e-5f

typedef __attribute__((ext_vector_type(8))) short bf16x8;
typedef __attribute__((ext_vector_type(4))) float f32x4;
typedef __attribute__((ext_vector_type(8))) unsigned short u16x8;

constexpr int Bn = 16, Cn = 96, Hn = 112, Wn = 112, HWn = Hn * Wn; // 12544
constexpr int NT = 64, TPI = HWn / NT;                             // 196

#define MFMA16(a, b, c) __builtin_amdgcn_mfma_f32_16x16x32_bf16((a), (b), (c), 0, 0, 0)

__device__ __forceinline__ ushort f2bf(float f) {
    __hip_bfloat16 h = __float2bfloat16(f);
    return __builtin_bit_cast(ushort, h);
}
__device__ __forceinline__ float bf2f(ushort u) {
    return __builtin_bit_cast(float, (unsigned)u << 16);
}
// tanh-form GELU: x * sigmoid(1.5957691*x + 0.0713548*x^3); |err| <= ~3e-4
__device__ __forceinline__ float gelu_f(float x) {
    float t = x * x;
    float z = x * fmaf(0.0713548162726f, t, 1.59576912161f);
    float e = __expf(-z);
    return __fdividef(x, 1.0f + e);
}
__device__ __forceinline__ uint pk2(float lo, float hi) {
    return (uint)f2bf(lo) | ((uint)f2bf(hi) << 16);
}

// ---------------- BN folding ----------------
// prm: A1[0:96] B1[96:192] Ag[192:384] Bg[384:576] A2[576:672] B2[672:768]
__global__ __launch_bounds__(256) void params_kernel(
    const float* __restrict__ b1, const float* __restrict__ g1, const float* __restrict__ be1,
    const float* __restrict__ m1, const float* __restrict__ v1,
    const float* __restrict__ bg, const float* __restrict__ gg, const float* __restrict__ beg,
    const float* __restrict__ mg, const float* __restrict__ vg,
    const float* __restrict__ b2, const float* __restrict__ g2, const float* __restrict__ be2,
    const float* __restrict__ m2, const float* __restrict__ v2,
    float* __restrict__ P)
{
    int t = threadIdx.x;
    if (t < 96) {
        float s = g1[t] * rsqrtf(v1[t] + EPSC);
        P[t]       = s;
        P[96 + t]  = (b1[t] - m1[t]) * s + be1[t];
        float s2 = g2[t] * rsqrtf(v2[t] + EPSC);
        P[576 + t] = s2;
        P[672 + t] = (b2[t] - m2[t]) * s2 + be2[t];
    }
    if (t < 192) {
        float s = gg[t] * rsqrtf(vg[t] + EPSC);
        P[192 + t] = s;
        P[384 + t] = (bg[t] - mg[t]) * s + beg[t];
    }
}

// ---------------- weight pack ----------------
// standard (w1, wg, wf1): element (mt,kc,lane,e) = W[mt*16 + lane%16][kc*32 + (lane>>4)*8 + e]
// permuted (w2, wf2):     k-col slot carries the producer's D-register channel
//   T = ((kc>>1)*4 + (kc&1)*2 + (e>>2))*16 + (lane>>4)*4 + (e&3)
// so a producer GEMM's D registers feed the consumer's B-frag with zero shuffles.
__global__ __launch_bounds__(256) void pack_kernel(
    const float* __restrict__ w1, const float* __restrict__ wg, const float* __restrict__ w2,
    const float* __restrict__ wf1, const float* __restrict__ wf2,
    ushort* __restrict__ dst)
{
    int idx = blockIdx.x * 256 + threadIdx.x;
    if (idx >= 138240) return;
    const float* src; int K, off; bool perm;
    if      (idx <   9216) { src = w1;  K =  96; off = 0;      perm = false; }
    else if (idx <  46080) { src = wg;  K = 192; off = 9216;   perm = false; }
    else if (idx <  64512) { src = w2;  K = 192; off = 46080;  perm = true;  }
    else if (idx < 101376) { src = wf1; K =  96; off = 64512;  perm = false; }
    else                   { src = wf2; K = 384; off = 101376; perm = true;  }
    int r = idx - off;
    int e = r & 7, lane = (r >> 3) & 63, tile = r >> 9;
    int KC = K / 32;
    int kc = tile % KC, mt = tile / KC;
    int row = mt * 16 + (lane & 15);
    int col;
    if (!perm) col = kc * 32 + (lane >> 4) * 8 + e;
    else       col = ((kc >> 1) * 4 + (kc & 1) * 2 + (e >> 2)) * 16 + (lane >> 4) * 4 + (e & 3);
    dst[idx] = f2bf(src[(size_t)row * K + col]);
}

// ---------------- parity mins ----------------
__global__ __launch_bounds__(256) void mins_kernel(
    const ushort* __restrict__ h, float* __restrict__ rmin2, float* __restrict__ cmin2)
{
    __shared__ __align__(16) ushort sl[112 * 96];
    int bid = blockIdx.x;            // Bn * 2 * 112
    int b = bid / 224, rem = bid % 224, mode = rem / 112, line = rem % 112;
    int t = threadIdx.x;
    if (mode == 0) {
        const ushort* base = h + ((size_t)b * HWn + line * Wn) * Cn;
        for (int v = t; v < 1344; v += 256)
            *(u16x8*)&sl[v * 8] = *(const u16x8*)&base[v * 8];
    } else {
        for (int v = t; v < 1344; v += 256) {
            int i = v / 12, g = v % 12;
            *(u16x8*)&sl[(i * 12 + g) * 8] =
                *(const u16x8*)&h[((size_t)b * HWn + i * Wn + line) * Cn + g * 8];
        }
    }
    __syncthreads();
    if (t < 192) {
        int c = t % 96, p = t / 96;
        float m = 1e30f;
        #pragma unroll 8
        for (int n = 0; n < 56; ++n) m = fminf(m, bf2f(sl[(p + 2 * n) * 96 + c]));
        float* dst = (mode == 0) ? rmin2 : cmin2;
        dst[(((size_t)b * 112 + line) * 2 + p) * 96 + c] = m;
    }
}

// ---------------- fc1: h = BN(W1 x) -> bf16 [b][hw][96] ----------------
__global__ __launch_bounds__(256) void fc1_kernel(
    const float* __restrict__ X, const ushort* __restrict__ w1p,
    const float* __restrict__ prm, ushort* __restrict__ hbuf)
{
    __shared__ __align__(16) ushort Hs[64 * 104];
    int bid = blockIdx.x, b = bid / TPI, hw0 = (bid % TPI) * NT;
    int t = threadIdx.x, lane = t & 63, wave = t >> 6;
    int wm = wave >> 1, wn = wave & 1, q = lane >> 4, sl = lane & 15;

    bf16x8 bfr[3][2];
    #pragma unroll
    for (int kc = 0; kc < 3; ++kc)
        #pragma unroll
        for (int nc = 0; nc < 2; ++nc) {
            int s = hw0 + wn * 32 + nc * 16 + sl;
            union { bf16x8 v; ushort u[8]; } f;
            #pragma unroll
            for (int e = 0; e < 8; ++e) {
                int c = kc * 32 + q * 8 + e;
                f.u[e] = f2bf(X[((size_t)b * Cn + c) * HWn + s]);
            }
            bfr[kc][nc] = f.v;
        }
    f32x4 acc[3][2] = {};
    #pragma unroll
    for (int kc = 0; kc < 3; ++kc)
        #pragma unroll
        for (int m = 0; m < 3; ++m) {
            bf16x8 af = *(const bf16x8*)&w1p[(((wm * 3 + m) * 3 + kc) * 64 + lane) * 8];
            acc[m][0] = MFMA16(af, bfr[kc][0], acc[m][0]);
            acc[m][1] = MFMA16(af, bfr[kc][1], acc[m][1]);
        }
    #pragma unroll
    for (int m = 0; m < 3; ++m) {
        int o0 = (wm * 3 + m) * 16 + q * 4;
        f32x4 a4 = *(const f32x4*)&prm[o0];
        f32x4 s4 = *(const f32x4*)&prm[96 + o0];
        #pragma unroll
        for (int nc = 0; nc < 2; ++nc) {
            int srow = wn * 32 + nc * 16 + sl;
            ushort4 pk;
            pk.x = f2bf(acc[m][nc][0] * a4[0] + s4[0]);
            pk.y = f2bf(acc[m][nc][1] * a4[1] + s4[1]);
            pk.z = f2bf(acc[m][nc][2] * a4[2] + s4[2]);
            pk.w = f2bf(acc[m][nc][3] * a4[3] + s4[3]);
            *(ushort4*)&Hs[srow * 104 + o0] = pk;
        }
    }
    __syncthreads();
    for (int v = t; v < 768; v += 256) {
        int s = v / 12, g = v % 12;
        *(u16x8*)&hbuf[((size_t)b * HWn + hw0 + s) * Cn + g * 8] = *(const u16x8*)&Hs[s * 104 + g * 8];
    }
}

// ---------------- grapher v10: cat(LDS) -> [fcg 2mt -> fc2 partial] -> reduce -> +res ----------------
// Chunk loop NOT unrolled (r9's full unroll caused scratch spill: VGPR=48, 1.1GB writes).
__global__ __launch_bounds__(256, 2) void grapher_kernel(
    const ushort* __restrict__ hbuf, const float* __restrict__ Xres,
    const ushort* __restrict__ wgp, const ushort* __restrict__ w2p,
    const float* __restrict__ prm,
    const float* __restrict__ cmin2, const float* __restrict__ rmin2,
    ushort* __restrict__ rbuf)
{
    __shared__ __align__(16) char smem[28672];       // max(cat 25.6KB, red 28.7KB)
    ushort* Xs = (ushort*)smem;                      // [64][200] cat tile
    float*  red = (float*)smem;                      // [4 waves][64 lanes][28]

    int bid = blockIdx.x, b = bid / TPI, hw0 = (bid % TPI) * NT;
    int t = threadIdx.x, lane = t & 63, wave = t >> 6;
    int wm = wave >> 1, wn = wave & 1, q = lane >> 4, sl = lane & 15;

    // ---- stage cat tile (coalesced) ----
    for (int v = t; v < 768; v += 256) {
        int s = v / 12, g = v % 12;
        u16x8 hv = *(const u16x8*)&hbuf[((size_t)b * HWn + hw0 + s) * Cn + g * 8];
        *(u16x8*)&Xs[s * 200 + g * 8] = hv;
        int pos = hw0 + s, i = pos / Wn, j = pos - i * Wn;
        const float* cm = &cmin2[(((size_t)b * 112 + j) * 2 + (i & 1)) * 96 + g * 8];
        const float* rm = &rmin2[(((size_t)b * 112 + i) * 2 + (j & 1)) * 96 + g * 8];
        union { u16x8 v; ushort u[8]; } hh, xx;
        hh.v = hv;
        #pragma unroll
        for (int e = 0; e < 8; ++e) {
            float hf = bf2f(hh.u[e]);
            xx.u[e] = f2bf(fmaxf(hf - cm[e], hf - rm[e]));   // mins include self => >= 0
        }
        *(u16x8*)&Xs[s * 200 + 96 + g * 8] = xx.v;
    }
    __syncthreads();                                  // bar1

    // ---- hoist cat B-frags ----
    bf16x8 cb[6][2];
    #pragma unroll
    for (int kc = 0; kc < 6; ++kc)
        #pragma unroll
        for (int n = 0; n < 2; ++n)
            cb[kc][n] = *(const bf16x8*)&Xs[(wn * 32 + n * 16 + sl) * 200 + kc * 32 + q * 8];

    // ---- 3 chunks: fcg (2 mt) -> gelu+pack -> fc2 partial ----
    f32x4 r2[6][2] = {};
    #pragma unroll 1
    for (int cc = 0; cc < 3; ++cc) {
        const int mt0 = wm * 6 + 2 * cc;
        f32x4 ga[2][2] = {};
        #pragma unroll
        for (int kc = 0; kc < 6; ++kc) {
            bf16x8 af0 = *(const bf16x8*)&wgp[(((mt0 + 0) * 6 + kc) * 64 + lane) * 8];
            bf16x8 af1 = *(const bf16x8*)&wgp[(((mt0 + 1) * 6 + kc) * 64 + lane) * 8];
            ga[0][0] = MFMA16(af0, cb[kc][0], ga[0][0]);
            ga[0][1] = MFMA16(af0, cb[kc][1], ga[0][1]);
            ga[1][0] = MFMA16(af1, cb[kc][0], ga[1][0]);
            ga[1][1] = MFMA16(af1, cb[kc][1], ga[1][1]);
        }
        uint gpk[2][2][2];
        #pragma unroll
        for (int mi = 0; mi < 2; ++mi) {
            int t0 = (mt0 + mi) * 16 + q * 4;
            f32x4 a4 = *(const f32x4*)&prm[192 + t0];
            f32x4 s4 = *(const f32x4*)&prm[384 + t0];
            #pragma unroll
            for (int n = 0; n < 2; ++n) {
                gpk[mi][n][0] = pk2(gelu_f(ga[mi][n][0] * a4[0] + s4[0]),
                                    gelu_f(ga[mi][n][1] * a4[1] + s4[1]));
                gpk[mi][n][1] = pk2(gelu_f(ga[mi][n][2] * a4[2] + s4[2]),
                                    gelu_f(ga[mi][n][3] * a4[3] + s4[3]));
            }
        }
        union { bf16x8 v; uint d[4]; } gb[2];
        #pragma unroll
        for (int n = 0; n < 2; ++n) {
            gb[n].d[0] = gpk[0][n][0]; gb[n].d[1] = gpk[0][n][1];
            gb[n].d[2] = gpk[1][n][0]; gb[n].d[3] = gpk[1][n][1];
        }
        const int kc2 = wm * 3 + cc;                  // M(kc2) == mt0 (verified)
        #pragma unroll
        for (int m = 0; m < 6; ++m) {
            bf16x8 af = *(const bf16x8*)&w2p[((m * 6 + kc2) * 64 + lane) * 8];
            r2[m][0] = MFMA16(af, gb[0].v, r2[m][0]);
            r2[m][1] = MFMA16(af, gb[1].v, r2[m][1]);
        }
    }

    __syncthreads();                                  // bar2: Xs reads done before red overwrite
    // ---- write complement m-half (constant indices per branch) ----
    {
        float* my = red + ((size_t)wave * 64 + lane) * 28;
        if (wm == 0) {
            #pragma unroll
            for (int mi = 0; mi < 3; ++mi)
                #pragma unroll
                for (int n = 0; n < 2; ++n)
                    *(f32x4*)&my[(mi * 2 + n) * 4] = r2[3 + mi][n];
        } else {
            #pragma unroll
            for (int mi = 0; mi < 3; ++mi)
                #pragma unroll
                for (int n = 0; n < 2; ++n)
                    *(f32x4*)&my[(mi * 2 + n) * 4] = r2[mi][n];
        }
    }
    __syncthreads();                                  // bar3
    // ---- read partner, add, BN + residual -> rbuf ----
    {
        const float* pr = red + ((size_t)(wave ^ 2) * 64 + lane) * 28;
        #pragma unroll
        for (int mi = 0; mi < 3; ++mi) {
            int m = wm * 3 + mi;
            int t0 = m * 16 + q * 4;
            f32x4 a4 = *(const f32x4*)&prm[576 + t0];
            f32x4 s4 = *(const f32x4*)&prm[672 + t0];
            #pragma unroll
            for (int n = 0; n < 2; ++n) {
                f32x4 part = *(const f32x4*)&pr[(mi * 2 + n) * 4];
                f32x4 own = (wm == 0) ? r2[mi][n] : r2[3 + mi][n];
                int s = hw0 + wn * 32 + n * 16 + sl;
                float rv[4];
                #pragma unroll
                for (int r = 0; r < 4; ++r)
                    rv[r] = (own[r] + part[r]) * a4[r] + s4[r]
                          + Xres[((size_t)b * 96 + t0 + r) * HWn + s];
                ushort4 pk;
                pk.x = f2bf(rv[0]); pk.y = f2bf(rv[1]); pk.z = f2bf(rv[2]); pk.w = f2bf(rv[3]);
                *(ushort4*)&rbuf[((size_t)b * HWn + s) * 96 + t0] = pk;
            }
        }
    }
}

// ---------------- ffn v10: stage r -> [ffn1 2mt -> gelu -> ffn2 partial] -> reduce ----------------
// Chunk loop NOT unrolled (spill fix).
__global__ __launch_bounds__(256, 2) void ffn_kernel(
    const ushort* __restrict__ rbuf,
    const ushort* __restrict__ wf1p, const float* __restrict__ bf1,
    const ushort* __restrict__ wf2p, const float* __restrict__ bf2,
    float* __restrict__ Out)
{
    __shared__ __align__(16) char smem[28672];       // max(Rs 13.3KB, red 28.7KB)
    ushort* Rs  = (ushort*)smem;                     // [64][104]
    float*  red = (float*)smem;

    int bid = blockIdx.x, b = bid / TPI, hw0 = (bid % TPI) * NT;
    int t = threadIdx.x, lane = t & 63, wave = t >> 6;
    int wm = wave >> 1, wn = wave & 1, q = lane >> 4, sl = lane & 15;

    for (int v = t; v < 768; v += 256) {
        int s = v / 12, g = v % 12;
        *(u16x8*)&Rs[s * 104 + g * 8] = *(const u16x8*)&rbuf[((size_t)b * HWn + hw0 + s) * Cn + g * 8];
    }
    __syncthreads();                                  // bar1

    bf16x8 rb[3][2];
    #pragma unroll
    for (int kc = 0; kc < 3; ++kc)
        #pragma unroll
        for (int n = 0; n < 2; ++n)
            rb[kc][n] = *(const bf16x8*)&Rs[(wn * 32 + n * 16 + sl) * 104 + kc * 32 + q * 8];

    f32x4 oacc[6][2] = {};
    #pragma unroll 1
    for (int cc = 0; cc < 6; ++cc) {
        const int mt0 = wm * 12 + 2 * cc;
        f32x4 a1[2][2] = {};
        #pragma unroll
        for (int kc = 0; kc < 3; ++kc) {
            bf16x8 af0 = *(const bf16x8*)&wf1p[(((mt0 + 0) * 3 + kc) * 64 + lane) * 8];
            bf16x8 af1 = *(const bf16x8*)&wf1p[(((mt0 + 1) * 3 + kc) * 64 + lane) * 8];
            a1[0][0] = MFMA16(af0, rb[kc][0], a1[0][0]);
            a1[0][1] = MFMA16(af0, rb[kc][1], a1[0][1]);
            a1[1][0] = MFMA16(af1, rb[kc][0], a1[1][0]);
            a1[1][1] = MFMA16(af1, rb[kc][1], a1[1][1]);
        }
        uint mpk[2][2][2];
        #pragma unroll
        for (int mi = 0; mi < 2; ++mi) {
            f32x4 b4 = *(const f32x4*)&bf1[(mt0 + mi) * 16 + q * 4];
            #pragma unroll
            for (int n = 0; n < 2; ++n) {
                mpk[mi][n][0] = pk2(gelu_f(a1[mi][n][0] + b4[0]), gelu_f(a1[mi][n][1] + b4[1]));
                mpk[mi][n][1] = pk2(gelu_f(a1[mi][n][2] + b4[2]), gelu_f(a1[mi][n][3] + b4[3]));
            }
        }
        union { bf16x8 v; uint d[4]; } mB[2];
        #pragma unroll
        for (int n = 0; n < 2; ++n) {
            mB[n].d[0] = mpk[0][n][0]; mB[n].d[1] = mpk[0][n][1];
            mB[n].d[2] = mpk[1][n][0]; mB[n].d[3] = mpk[1][n][1];
        }
        const int kc2 = wm * 6 + cc;                  // M(kc2) == mt0 (verified)
        #pragma unroll
        for (int m = 0; m < 6; ++m) {
            bf16x8 af = *(const bf16x8*)&wf2p[((m * 12 + kc2) * 64 + lane) * 8];
            oacc[m][0] = MFMA16(af, mB[0].v, oacc[m][0]);
            oacc[m][1] = MFMA16(af, mB[1].v, oacc[m][1]);
        }
    }

    __syncthreads();                                  // bar2: Rs reads done before red overwrite
    {
        float* my = red + ((size_t)wave * 64 + lane) * 28;
        if (wm == 0) {
            #pragma unroll
            for (int mi = 0; mi < 3; ++mi)
                #pragma unroll
                for (int n = 0; n < 2; ++n)
                    *(f32x4*)&my[(mi * 2 + n) * 4] = oacc[3 + mi][n];
        } else {
            #pragma unroll
            for (int mi = 0; mi < 3; ++mi)
                #pragma unroll
                for (int n = 0; n < 2; ++n)
                    *(f32x4*)&my[(mi * 2 + n) * 4] = oacc[mi][n];
        }
    }
    __syncthreads();                                  // bar3
    {
        const float* pr = red + ((size_t)(wave ^ 2) * 64 + lane) * 28;
        #pragma unroll
        for (int mi = 0; mi < 3; ++mi) {
            int m = wm * 3 + mi;
            int t0 = m * 16 + q * 4;
            f32x4 b4 = *(const f32x4*)&bf2[t0];
            #pragma unroll
            for (int n = 0; n < 2; ++n) {
                f32x4 part = *(const f32x4*)&pr[(mi * 2 + n) * 4];
                f32x4 own = (wm == 0) ? oacc[mi][n] : oacc[3 + mi][n];
                int s = hw0 + wn * 32 + n * 16 + sl;
                #pragma unroll
                for (int r = 0; r < 4; ++r)
                    Out[((size_t)b * 96 + t0 + r) * HWn + s] = own[r] + part[r] + b4[r];
            }
        }
    }
}

extern "C" void kernel_launch(void* const* d_in, const int* in_sizes, int n_in,
                              void* d_out, int out_size, void* d_ws, size_t ws_size,
                              hipStream_t stream) {
    (void)in_sizes; (void)n_in; (void)out_size; (void)ws_size;
    const float* x   = (const float*)d_in[0];
    const float* w1  = (const float*)d_in[1];
    const float* b1  = (const float*)d_in[2];
    const float* g1  = (const float*)d_in[3];
    const float* be1 = (const float*)d_in[4];
    const float* m1  = (const float*)d_in[5];
    const float* v1  = (const float*)d_in[6];
    const float* wg  = (const float*)d_in[7];
    const float* bg  = (const float*)d_in[8];
    const float* gg  = (const float*)d_in[9];
    const float* beg = (const float*)d_in[10];
    const float* mg  = (const float*)d_in[11];
    const float* vg  = (const float*)d_in[12];
    const float* w2  = (const float*)d_in[13];
    const float* b2  = (const float*)d_in[14];
    const float* g2  = (const float*)d_in[15];
    const float* be2 = (const float*)d_in[16];
    const float* m2  = (const float*)d_in[17];
    const float* v2  = (const float*)d_in[18];
    const float* wf1 = (const float*)d_in[19];
    const float* bf1 = (const float*)d_in[20];
    const float* wf2 = (const float*)d_in[21];
    const float* bf2 = (const float*)d_in[22];
    float* out = (float*)d_out;

    char* base = (char*)d_ws;
    const size_t H_BYTES   = (size_t)Bn * HWn * Cn * 2;
    const size_t MIN_BYTES = (size_t)Bn * 112 * 2 * 96 * 4;
    ushort* hbuf  = (ushort*)base;                         // h, overwritten by r
    float*  rmin2 = (float*)(base + H_BYTES);
    float*  cmin2 = (float*)(base + H_BYTES + MIN_BYTES);
    float*  prm   = (float*)(base + H_BYTES + 2 * MIN_BYTES);
    ushort* wpack = (ushort*)(base + H_BYTES + 2 * MIN_BYTES + 3072);
    ushort* w1p  = wpack;
    ushort* wgp  = wpack + 9216;
    ushort* w2p  = wpack + 46080;
    ushort* wf1p = wpack + 64512;
    ushort* wf2p = wpack + 101376;

    params_kernel<<<dim3(1), dim3(256), 0, stream>>>(
        b1, g1, be1, m1, v1, bg, gg, beg, mg, vg, b2, g2, be2, m2, v2, prm);
    pack_kernel<<<dim3(540), dim3(256), 0, stream>>>(w1, wg, w2, wf1, wf2, wpack);

    dim3 blk(256);
    fc1_kernel<<<dim3(Bn * TPI), blk, 0, stream>>>(x, w1p, prm, hbuf);
    mins_kernel<<<dim3(Bn * 2 * 112), blk, 0, stream>>>(hbuf, rmin2, cmin2);
    grapher_kernel<<<dim3(Bn * TPI), blk, 0, stream>>>(hbuf, x, wgp, w2p,
                                                       prm, cmin2, rmin2, hbuf);
    ffn_kernel<<<dim3(Bn * TPI), blk, 0, stream>>>(hbuf, wf1p, bf1, wf2p, bf2, out);
}

// Round 11
// 289.559 us; speedup vs baseline: 1.9644x; 1.0770x over previous
//
#include <hip/hip_runtime.h>
#include <hip/hip_bf16.h>
#include <math.h>

#define EPSC 1e-5f

typedef __attribute__((ext_vector_type(8))) short bf16x8;
typedef __attribute__((ext_vector_type(4))) float f32x4;
typedef __attribute__((ext_vector_type(8))) unsigned short u16x8;

constexpr int Bn = 16, Cn = 96, Hn = 112, Wn = 112, HWn = Hn * Wn; // 12544
constexpr int NT = 64, TPI = HWn / NT;                             // 196

#define MFMA16(a, b, c) __builtin_amdgcn_mfma_f32_16x16x32_bf16((a), (b), (c), 0, 0, 0)

__device__ __forceinline__ ushort f2bf(float f) {
    __hip_bfloat16 h = __float2bfloat16(f);
    return __builtin_bit_cast(ushort, h);
}
__device__ __forceinline__ float bf2f(ushort u) {
    return __builtin_bit_cast(float, (unsigned)u << 16);
}
// tanh-form GELU: x * sigmoid(1.5957691*x + 0.0713548*x^3); |err| <= ~3e-4
__device__ __forceinline__ float gelu_f(float x) {
    float t = x * x;
    float z = x * fmaf(0.0713548162726f, t, 1.59576912161f);
    float e = __expf(-z);
    return __fdividef(x, 1.0f + e);
}

// ---------------- BN folding ----------------
// prm: A1[0:96] B1[96:192] Ag[192:384] Bg[384:576] A2[576:672] B2[672:768]
__global__ __launch_bounds__(256) void params_kernel(
    const float* __restrict__ b1, const float* __restrict__ g1, const float* __restrict__ be1,
    const float* __restrict__ m1, const float* __restrict__ v1,
    const float* __restrict__ bg, const float* __restrict__ gg, const float* __restrict__ beg,
    const float* __restrict__ mg, const float* __restrict__ vg,
    const float* __restrict__ b2, const float* __restrict__ g2, const float* __restrict__ be2,
    const float* __restrict__ m2, const float* __restrict__ v2,
    float* __restrict__ P)
{
    int t = threadIdx.x;
    if (t < 96) {
        float s = g1[t] * rsqrtf(v1[t] + EPSC);
        P[t]       = s;
        P[96 + t]  = (b1[t] - m1[t]) * s + be1[t];
        float s2 = g2[t] * rsqrtf(v2[t] + EPSC);
        P[576 + t] = s2;
        P[672 + t] = (b2[t] - m2[t]) * s2 + be2[t];
    }
    if (t < 192) {
        float s = gg[t] * rsqrtf(vg[t] + EPSC);
        P[192 + t] = s;
        P[384 + t] = (bg[t] - mg[t]) * s + beg[t];
    }
}

// ---------------- weight pack: fragment order [mt][kc][lane][8], bf16 (all standard) ----------------
// element (mt,kc,lane,e) = W[mt*16 + lane%16][kc*32 + (lane>>4)*8 + e]
__global__ __launch_bounds__(256) void pack_kernel(
    const float* __restrict__ w1, const float* __restrict__ wg, const float* __restrict__ w2,
    const float* __restrict__ wf1, const float* __restrict__ wf2,
    ushort* __restrict__ dst)
{
    int idx = blockIdx.x * 256 + threadIdx.x;
    if (idx >= 138240) return;
    const float* src; int K, off;
    if      (idx <   9216) { src = w1;  K =  96; off = 0;      }
    else if (idx <  46080) { src = wg;  K = 192; off = 9216;   }
    else if (idx <  64512) { src = w2;  K = 192; off = 46080;  }
    else if (idx < 101376) { src = wf1; K =  96; off = 64512;  }
    else                   { src = wf2; K = 384; off = 101376; }
    int r = idx - off;
    int e = r & 7, lane = (r >> 3) & 63, tile = r >> 9;
    int KC = K / 32;
    int kc = tile % KC, mt = tile / KC;
    int row = mt * 16 + (lane & 15);
    int col = kc * 32 + (lane >> 4) * 8 + e;
    dst[idx] = f2bf(src[(size_t)row * K + col]);
}

// ---------------- parity mins ----------------
__global__ __launch_bounds__(256) void mins_kernel(
    const ushort* __restrict__ h, float* __restrict__ rmin2, float* __restrict__ cmin2)
{
    __shared__ __align__(16) ushort sl[112 * 96];
    int bid = blockIdx.x;            // Bn * 2 * 112
    int b = bid / 224, rem = bid % 224, mode = rem / 112, line = rem % 112;
    int t = threadIdx.x;
    if (mode == 0) {
        const ushort* base = h + ((size_t)b * HWn + line * Wn) * Cn;
        for (int v = t; v < 1344; v += 256)
            *(u16x8*)&sl[v * 8] = *(const u16x8*)&base[v * 8];
    } else {
        for (int v = t; v < 1344; v += 256) {
            int i = v / 12, g = v % 12;
            *(u16x8*)&sl[(i * 12 + g) * 8] =
                *(const u16x8*)&h[((size_t)b * HWn + i * Wn + line) * Cn + g * 8];
        }
    }
    __syncthreads();
    if (t < 192) {
        int c = t % 96, p = t / 96;
        float m = 1e30f;
        #pragma unroll 8
        for (int n = 0; n < 56; ++n) m = fminf(m, bf2f(sl[(p + 2 * n) * 96 + c]));
        float* dst = (mode == 0) ? rmin2 : cmin2;
        dst[(((size_t)b * 112 + line) * 2 + p) * 96 + c] = m;
    }
}

// ---------------- fc1: h = BN(W1 x) -> bf16 [b][hw][96] ----------------
__global__ __launch_bounds__(256) void fc1_kernel(
    const float* __restrict__ X, const ushort* __restrict__ w1p,
    const float* __restrict__ prm, ushort* __restrict__ hbuf)
{
    __shared__ __align__(16) ushort Hs[64 * 104];
    int bid = blockIdx.x, b = bid / TPI, hw0 = (bid % TPI) * NT;
    int t = threadIdx.x, lane = t & 63, wave = t >> 6;
    int wm = wave >> 1, wn = wave & 1, q = lane >> 4, sl = lane & 15;

    bf16x8 bfr[3][2];
    #pragma unroll
    for (int kc = 0; kc < 3; ++kc)
        #pragma unroll
        for (int nc = 0; nc < 2; ++nc) {
            int s = hw0 + wn * 32 + nc * 16 + sl;
            union { bf16x8 v; ushort u[8]; } f;
            #pragma unroll
            for (int e = 0; e < 8; ++e) {
                int c = kc * 32 + q * 8 + e;
                f.u[e] = f2bf(X[((size_t)b * Cn + c) * HWn + s]);
            }
            bfr[kc][nc] = f.v;
        }
    f32x4 acc[3][2] = {};
    #pragma unroll
    for (int kc = 0; kc < 3; ++kc)
        #pragma unroll
        for (int m = 0; m < 3; ++m) {
            bf16x8 af = *(const bf16x8*)&w1p[(((wm * 3 + m) * 3 + kc) * 64 + lane) * 8];
            acc[m][0] = MFMA16(af, bfr[kc][0], acc[m][0]);
            acc[m][1] = MFMA16(af, bfr[kc][1], acc[m][1]);
        }
    #pragma unroll
    for (int m = 0; m < 3; ++m) {
        int o0 = (wm * 3 + m) * 16 + q * 4;
        f32x4 a4 = *(const f32x4*)&prm[o0];
        f32x4 s4 = *(const f32x4*)&prm[96 + o0];
        #pragma unroll
        for (int nc = 0; nc < 2; ++nc) {
            int srow = wn * 32 + nc * 16 + sl;
            ushort4 pk;
            pk.x = f2bf(acc[m][nc][0] * a4[0] + s4[0]);
            pk.y = f2bf(acc[m][nc][1] * a4[1] + s4[1]);
            pk.z = f2bf(acc[m][nc][2] * a4[2] + s4[2]);
            pk.w = f2bf(acc[m][nc][3] * a4[3] + s4[3]);
            *(ushort4*)&Hs[srow * 104 + o0] = pk;
        }
    }
    __syncthreads();
    for (int v = t; v < 768; v += 256) {
        int s = v / 12, g = v % 12;
        *(u16x8*)&hbuf[((size_t)b * HWn + hw0 + s) * Cn + g * 8] = *(const u16x8*)&Hs[s * 104 + g * 8];
    }
}

// ---------------- tail: cat -> fcg+BN+GELU -> fc2+BN+res (r in LDS) -> ffn1+GELU -> ffn2 -> out ----
// Merged r5 grapher + r5 ffn; r never touches HBM. LDS layout:
//   Xs  = S[0 .. 12800)          cat tile [64][200]; later holds r-tile (same layout)
//   Gs  = S[12800 .. 25600)      g tile [64][200]
//   mid slabs alias Gs region:   slab0 = S+12800, slab1 = S+12800+6656 ([64][104] each)
// Gs is fully consumed (fc2) before the barrier preceding the first slab write.
__global__ __launch_bounds__(256) void tail_kernel(
    const ushort* __restrict__ hbuf, const float* __restrict__ Xres,
    const ushort* __restrict__ wgp, const ushort* __restrict__ w2p,
    const ushort* __restrict__ wf1p, const float* __restrict__ bf1,
    const ushort* __restrict__ wf2p, const float* __restrict__ bf2,
    const float* __restrict__ prm,
    const float* __restrict__ cmin2, const float* __restrict__ rmin2,
    float* __restrict__ Out)
{
    __shared__ __align__(16) ushort S[26112];        // 52.2 KB
    ushort* Xs = S;
    ushort* Gs = S + 12800;

    int bid = blockIdx.x, b = bid / TPI, hw0 = (bid % TPI) * NT;
    int t = threadIdx.x, lane = t & 63, wave = t >> 6;
    int wm = wave >> 1, wn = wave & 1, q = lane >> 4, sl = lane & 15;

    // ---- stage cat tile ----
    for (int v = t; v < 768; v += 256) {
        int s = v / 12, g = v % 12;
        u16x8 hv = *(const u16x8*)&hbuf[((size_t)b * HWn + hw0 + s) * Cn + g * 8];
        *(u16x8*)&Xs[s * 200 + g * 8] = hv;
        int pos = hw0 + s, i = pos / Wn, j = pos - i * Wn;
        const float* cm = &cmin2[(((size_t)b * 112 + j) * 2 + (i & 1)) * 96 + g * 8];
        const float* rm = &rmin2[(((size_t)b * 112 + i) * 2 + (j & 1)) * 96 + g * 8];
        union { u16x8 v; ushort u[8]; } hh, xx;
        hh.v = hv;
        #pragma unroll
        for (int e = 0; e < 8; ++e) {
            float hf = bf2f(hh.u[e]);
            xx.u[e] = f2bf(fmaxf(hf - cm[e], hf - rm[e]));   // mins include self => >= 0
        }
        *(u16x8*)&Xs[s * 200 + 96 + g * 8] = xx.v;
    }
    __syncthreads();                                  // bar1

    // ---- fcg: M=192, K=192 -> Gs ----
    {
        f32x4 acc[6][2] = {};
        #pragma unroll
        for (int kc = 0; kc < 6; ++kc) {
            bf16x8 b0 = *(const bf16x8*)&Xs[(wn * 32 + sl) * 200 + kc * 32 + q * 8];
            bf16x8 b1 = *(const bf16x8*)&Xs[(wn * 32 + 16 + sl) * 200 + kc * 32 + q * 8];
            #pragma unroll
            for (int m = 0; m < 6; ++m) {
                bf16x8 af = *(const bf16x8*)&wgp[(((wm * 6 + m) * 6 + kc) * 64 + lane) * 8];
                acc[m][0] = MFMA16(af, b0, acc[m][0]);
                acc[m][1] = MFMA16(af, b1, acc[m][1]);
            }
        }
        #pragma unroll
        for (int m = 0; m < 6; ++m) {
            int o0 = (wm * 6 + m) * 16 + q * 4;
            f32x4 a4 = *(const f32x4*)&prm[192 + o0];
            f32x4 s4 = *(const f32x4*)&prm[384 + o0];
            #pragma unroll
            for (int nc = 0; nc < 2; ++nc) {
                int srow = wn * 32 + nc * 16 + sl;
                ushort4 pk;
                pk.x = f2bf(gelu_f(acc[m][nc][0] * a4[0] + s4[0]));
                pk.y = f2bf(gelu_f(acc[m][nc][1] * a4[1] + s4[1]));
                pk.z = f2bf(gelu_f(acc[m][nc][2] * a4[2] + s4[2]));
                pk.w = f2bf(gelu_f(acc[m][nc][3] * a4[3] + s4[3]));
                *(ushort4*)&Gs[srow * 200 + o0] = pk;
            }
        }
    }
    __syncthreads();                                  // bar2

    // ---- fc2: M=96, K=192; +BN+residual -> r-tile into Xs ----
    {
        f32x4 acc2[3][2] = {};
        #pragma unroll
        for (int kc = 0; kc < 6; ++kc) {
            bf16x8 b0 = *(const bf16x8*)&Gs[(wn * 32 + sl) * 200 + kc * 32 + q * 8];
            bf16x8 b1 = *(const bf16x8*)&Gs[(wn * 32 + 16 + sl) * 200 + kc * 32 + q * 8];
            #pragma unroll
            for (int m = 0; m < 3; ++m) {
                bf16x8 af = *(const bf16x8*)&w2p[(((wm * 3 + m) * 6 + kc) * 64 + lane) * 8];
                acc2[m][0] = MFMA16(af, b0, acc2[m][0]);
                acc2[m][1] = MFMA16(af, b1, acc2[m][1]);
            }
        }
        #pragma unroll
        for (int m = 0; m < 3; ++m) {
            int o0 = (wm * 3 + m) * 16 + q * 4;
            f32x4 a4 = *(const f32x4*)&prm[576 + o0];
            f32x4 s4 = *(const f32x4*)&prm[672 + o0];
            #pragma unroll
            for (int nc = 0; nc < 2; ++nc) {
                int srow = wn * 32 + nc * 16 + sl, sgl = hw0 + srow;
                ushort4 pk;
                float r0 = acc2[m][nc][0] * a4[0] + s4[0] + Xres[((size_t)b * Cn + o0 + 0) * HWn + sgl];
                float r1 = acc2[m][nc][1] * a4[1] + s4[1] + Xres[((size_t)b * Cn + o0 + 1) * HWn + sgl];
                float r2 = acc2[m][nc][2] * a4[2] + s4[2] + Xres[((size_t)b * Cn + o0 + 2) * HWn + sgl];
                float r3 = acc2[m][nc][3] * a4[3] + s4[3] + Xres[((size_t)b * Cn + o0 + 3) * HWn + sgl];
                pk.x = f2bf(r0); pk.y = f2bf(r1); pk.z = f2bf(r2); pk.w = f2bf(r3);
                *(ushort4*)&Xs[srow * 200 + o0] = pk;
            }
        }
    }
    __syncthreads();                                  // bar3: r-tile complete; Gs free

    // ---- ffn: hoist r B-frags from Xs r-tile (stride 200) ----
    bf16x8 rb[3][2];
    #pragma unroll
    for (int kc = 0; kc < 3; ++kc) {
        rb[kc][0] = *(const bf16x8*)&Xs[(wn * 32 + sl) * 200 + kc * 32 + q * 8];
        rb[kc][1] = *(const bf16x8*)&Xs[(wn * 32 + 16 + sl) * 200 + kc * 32 + q * 8];
    }

    // ---- 4 chunks of 96 mid channels; double-buffered slabs alias Gs ----
    f32x4 acc2[3][2] = {};
    for (int c = 0; c < 4; ++c) {
        f32x4 a1[3][2] = {};
        #pragma unroll
        for (int kc = 0; kc < 3; ++kc)
            #pragma unroll
            for (int m = 0; m < 3; ++m) {
                bf16x8 af = *(const bf16x8*)&wf1p[(((c * 6 + wm * 3 + m) * 3 + kc) * 64 + lane) * 8];
                a1[m][0] = MFMA16(af, rb[kc][0], a1[m][0]);
                a1[m][1] = MFMA16(af, rb[kc][1], a1[m][1]);
            }
        ushort* mc = Gs + (c & 1) * 6656;
        #pragma unroll
        for (int m = 0; m < 3; ++m) {
            int ol = (wm * 3 + m) * 16 + q * 4;          // 0..95 within chunk
            f32x4 b4 = *(const f32x4*)&bf1[c * 96 + ol];
            #pragma unroll
            for (int nc = 0; nc < 2; ++nc) {
                int srow = wn * 32 + nc * 16 + sl;
                ushort4 pk;
                pk.x = f2bf(gelu_f(a1[m][nc][0] + b4[0]));
                pk.y = f2bf(gelu_f(a1[m][nc][1] + b4[1]));
                pk.z = f2bf(gelu_f(a1[m][nc][2] + b4[2]));
                pk.w = f2bf(gelu_f(a1[m][nc][3] + b4[3]));
                *(ushort4*)&mc[srow * 104 + ol] = pk;
            }
        }
        __syncthreads();                              // 1 barrier per chunk (r5 proof)
        #pragma unroll
        for (int kc = 0; kc < 3; ++kc) {
            bf16x8 m0 = *(const bf16x8*)&mc[(wn * 32 + sl) * 104 + kc * 32 + q * 8];
            bf16x8 m1 = *(const bf16x8*)&mc[(wn * 32 + 16 + sl) * 104 + kc * 32 + q * 8];
            #pragma unroll
            for (int m = 0; m < 3; ++m) {
                bf16x8 af = *(const bf16x8*)&wf2p[(((wm * 3 + m) * 12 + c * 3 + kc) * 64 + lane) * 8];
                acc2[m][0] = MFMA16(af, m0, acc2[m][0]);
                acc2[m][1] = MFMA16(af, m1, acc2[m][1]);
            }
        }
    }
    #pragma unroll
    for (int m = 0; m < 3; ++m) {
        int o0 = (wm * 3 + m) * 16 + q * 4;
        f32x4 b4 = *(const f32x4*)&bf2[o0];
        #pragma unroll
        for (int nc = 0; nc < 2; ++nc) {
            int sgl = hw0 + wn * 32 + nc * 16 + sl;
            Out[((size_t)b * Cn + o0 + 0) * HWn + sgl] = acc2[m][nc][0] + b4[0];
            Out[((size_t)b * Cn + o0 + 1) * HWn + sgl] = acc2[m][nc][1] + b4[1];
            Out[((size_t)b * Cn + o0 + 2) * HWn + sgl] = acc2[m][nc][2] + b4[2];
            Out[((size_t)b * Cn + o0 + 3) * HWn + sgl] = acc2[m][nc][3] + b4[3];
        }
    }
}

extern "C" void kernel_launch(void* const* d_in, const int* in_sizes, int n_in,
                              void* d_out, int out_size, void* d_ws, size_t ws_size,
                              hipStream_t stream) {
    (void)in_sizes; (void)n_in; (void)out_size; (void)ws_size;
    const float* x   = (const float*)d_in[0];
    const float* w1  = (const float*)d_in[1];
    const float* b1  = (const float*)d_in[2];
    const float* g1  = (const float*)d_in[3];
    const float* be1 = (const float*)d_in[4];
    const float* m1  = (const float*)d_in[5];
    const float* v1  = (const float*)d_in[6];
    const float* wg  = (const float*)d_in[7];
    const float* bg  = (const float*)d_in[8];
    const float* gg  = (const float*)d_in[9];
    const float* beg = (const float*)d_in[10];
    const float* mg  = (const float*)d_in[11];
    const float* vg  = (const float*)d_in[12];
    const float* w2  = (const float*)d_in[13];
    const float* b2  = (const float*)d_in[14];
    const float* g2  = (const float*)d_in[15];
    const float* be2 = (const float*)d_in[16];
    const float* m2  = (const float*)d_in[17];
    const float* v2  = (const float*)d_in[18];
    const float* wf1 = (const float*)d_in[19];
    const float* bf1 = (const float*)d_in[20];
    const float* wf2 = (const float*)d_in[21];
    const float* bf2 = (const float*)d_in[22];
    float* out = (float*)d_out;

    char* base = (char*)d_ws;
    const size_t H_BYTES   = (size_t)Bn * HWn * Cn * 2;
    const size_t MIN_BYTES = (size_t)Bn * 112 * 2 * 96 * 4;
    ushort* hbuf  = (ushort*)base;
    float*  rmin2 = (float*)(base + H_BYTES);
    float*  cmin2 = (float*)(base + H_BYTES + MIN_BYTES);
    float*  prm   = (float*)(base + H_BYTES + 2 * MIN_BYTES);
    ushort* wpack = (ushort*)(base + H_BYTES + 2 * MIN_BYTES + 3072);
    ushort* w1p  = wpack;
    ushort* wgp  = wpack + 9216;
    ushort* w2p  = wpack + 46080;
    ushort* wf1p = wpack + 64512;
    ushort* wf2p = wpack + 101376;

    params_kernel<<<dim3(1), dim3(256), 0, stream>>>(
        b1, g1, be1, m1, v1, bg, gg, beg, mg, vg, b2, g2, be2, m2, v2, prm);
    pack_kernel<<<dim3(540), dim3(256), 0, stream>>>(w1, wg, w2, wf1, wf2, wpack);

    dim3 blk(256);
    fc1_kernel<<<dim3(Bn * TPI), blk, 0, stream>>>(x, w1p, prm, hbuf);
    mins_kernel<<<dim3(Bn * 2 * 112), blk, 0, stream>>>(hbuf, rmin2, cmin2);
    tail_kernel<<<dim3(Bn * TPI), blk, 0, stream>>>(hbuf, x, wgp, w2p,
                                                    wf1p, bf1, wf2p, bf2,
                                                    prm, cmin2, rmin2, out);
}

// Round 12
// 194.642 us; speedup vs baseline: 2.9223x; 1.4876x over previous
//
#include <hip/hip_runtime.h>
#include <hip/hip_bf16.h>
#include <math.h>

#define EPSC 1e-5f

typedef __attribute__((ext_vector_type(8))) short bf16x8;
typedef __attribute__((ext_vector_type(4))) float f32x4;
typedef __attribute__((ext_vector_type(8))) unsigned short u16x8;

constexpr int Bn = 16, Cn = 96, Hn = 112, Wn = 112, HWn = Hn * Wn; // 12544
constexpr int NT = 64, TPI = HWn / NT;                             // 196

#define MFMA16(a, b, c) __builtin_amdgcn_mfma_f32_16x16x32_bf16((a), (b), (c), 0, 0, 0)

__device__ __forceinline__ ushort f2bf(float f) {
    __hip_bfloat16 h = __float2bfloat16(f);
    return __builtin_bit_cast(ushort, h);
}
__device__ __forceinline__ float bf2f(ushort u) {
    return __builtin_bit_cast(float, (unsigned)u << 16);
}
// tanh-form GELU: x * sigmoid(1.5957691*x + 0.0713548*x^3); |err| <= ~3e-4
__device__ __forceinline__ float gelu_f(float x) {
    float t = x * x;
    float z = x * fmaf(0.0713548162726f, t, 1.59576912161f);
    float e = __expf(-z);
    return __fdividef(x, 1.0f + e);
}

// ---------------- BN folding ----------------
// prm: A1[0:96] B1[96:192] Ag[192:384] Bg[384:576] A2[576:672] B2[672:768]
__global__ __launch_bounds__(256) void params_kernel(
    const float* __restrict__ b1, const float* __restrict__ g1, const float* __restrict__ be1,
    const float* __restrict__ m1, const float* __restrict__ v1,
    const float* __restrict__ bg, const float* __restrict__ gg, const float* __restrict__ beg,
    const float* __restrict__ mg, const float* __restrict__ vg,
    const float* __restrict__ b2, const float* __restrict__ g2, const float* __restrict__ be2,
    const float* __restrict__ m2, const float* __restrict__ v2,
    float* __restrict__ P)
{
    int t = threadIdx.x;
    if (t < 96) {
        float s = g1[t] * rsqrtf(v1[t] + EPSC);
        P[t]       = s;
        P[96 + t]  = (b1[t] - m1[t]) * s + be1[t];
        float s2 = g2[t] * rsqrtf(v2[t] + EPSC);
        P[576 + t] = s2;
        P[672 + t] = (b2[t] - m2[t]) * s2 + be2[t];
    }
    if (t < 192) {
        float s = gg[t] * rsqrtf(vg[t] + EPSC);
        P[192 + t] = s;
        P[384 + t] = (bg[t] - mg[t]) * s + beg[t];
    }
}

// ---------------- weight pack: fragment order [mt][kc][lane][8], bf16 ----------------
__global__ __launch_bounds__(256) void pack_kernel(
    const float* __restrict__ w1, const float* __restrict__ wg, const float* __restrict__ w2,
    const float* __restrict__ wf1, const float* __restrict__ wf2,
    ushort* __restrict__ dst)
{
    int idx = blockIdx.x * 256 + threadIdx.x;
    if (idx >= 138240) return;
    const float* src; int K, off;
    if      (idx <   9216) { src = w1;  K =  96; off = 0;      }
    else if (idx <  46080) { src = wg;  K = 192; off = 9216;   }
    else if (idx <  64512) { src = w2;  K = 192; off = 46080;  }
    else if (idx < 101376) { src = wf1; K =  96; off = 64512;  }
    else                   { src = wf2; K = 384; off = 101376; }
    int r = idx - off;
    int e = r & 7, lane = (r >> 3) & 63, tile = r >> 9;
    int KC = K / 32;
    int kc = tile % KC, mt = tile / KC;
    int row = mt * 16 + (lane & 15);
    int col = kc * 32 + (lane >> 4) * 8 + e;
    dst[idx] = f2bf(src[(size_t)row * K + col]);
}

// ---------------- parity mins ----------------
__global__ __launch_bounds__(256) void mins_kernel(
    const ushort* __restrict__ h, float* __restrict__ rmin2, float* __restrict__ cmin2)
{
    __shared__ __align__(16) ushort sl[112 * 96];
    int bid = blockIdx.x;            // Bn * 2 * 112
    int b = bid / 224, rem = bid % 224, mode = rem / 112, line = rem % 112;
    int t = threadIdx.x;
    if (mode == 0) {
        const ushort* base = h + ((size_t)b * HWn + line * Wn) * Cn;
        for (int v = t; v < 1344; v += 256)
            *(u16x8*)&sl[v * 8] = *(const u16x8*)&base[v * 8];
    } else {
        for (int v = t; v < 1344; v += 256) {
            int i = v / 12, g = v % 12;
            *(u16x8*)&sl[(i * 12 + g) * 8] =
                *(const u16x8*)&h[((size_t)b * HWn + i * Wn + line) * Cn + g * 8];
        }
    }
    __syncthreads();
    if (t < 192) {
        int c = t % 96, p = t / 96;
        float m = 1e30f;
        #pragma unroll 8
        for (int n = 0; n < 56; ++n) m = fminf(m, bf2f(sl[(p + 2 * n) * 96 + c]));
        float* dst = (mode == 0) ? rmin2 : cmin2;
        dst[(((size_t)b * 112 + line) * 2 + p) * 96 + c] = m;
    }
}

// ---------------- fc1: h = BN(W1 x) -> bf16 [b][hw][96] ----------------
__global__ __launch_bounds__(256) void fc1_kernel(
    const float* __restrict__ X, const ushort* __restrict__ w1p,
    const float* __restrict__ prm, ushort* __restrict__ hbuf)
{
    __shared__ __align__(16) ushort Hs[64 * 104];
    int bid = blockIdx.x, b = bid / TPI, hw0 = (bid % TPI) * NT;
    int t = threadIdx.x, lane = t & 63, wave = t >> 6;
    int wm = wave >> 1, wn = wave & 1, q = lane >> 4, sl = lane & 15;

    bf16x8 bfr[3][2];
    #pragma unroll
    for (int kc = 0; kc < 3; ++kc)
        #pragma unroll
        for (int nc = 0; nc < 2; ++nc) {
            int s = hw0 + wn * 32 + nc * 16 + sl;
            union { bf16x8 v; ushort u[8]; } f;
            #pragma unroll
            for (int e = 0; e < 8; ++e) {
                int c = kc * 32 + q * 8 + e;
                f.u[e] = f2bf(X[((size_t)b * Cn + c) * HWn + s]);
            }
            bfr[kc][nc] = f.v;
        }
    f32x4 acc[3][2] = {};
    #pragma unroll
    for (int kc = 0; kc < 3; ++kc)
        #pragma unroll
        for (int m = 0; m < 3; ++m) {
            bf16x8 af = *(const bf16x8*)&w1p[(((wm * 3 + m) * 3 + kc) * 64 + lane) * 8];
            acc[m][0] = MFMA16(af, bfr[kc][0], acc[m][0]);
            acc[m][1] = MFMA16(af, bfr[kc][1], acc[m][1]);
        }
    #pragma unroll
    for (int m = 0; m < 3; ++m) {
        int o0 = (wm * 3 + m) * 16 + q * 4;
        f32x4 a4 = *(const f32x4*)&prm[o0];
        f32x4 s4 = *(const f32x4*)&prm[96 + o0];
        #pragma unroll
        for (int nc = 0; nc < 2; ++nc) {
            int srow = wn * 32 + nc * 16 + sl;
            ushort4 pk;
            pk.x = f2bf(acc[m][nc][0] * a4[0] + s4[0]);
            pk.y = f2bf(acc[m][nc][1] * a4[1] + s4[1]);
            pk.z = f2bf(acc[m][nc][2] * a4[2] + s4[2]);
            pk.w = f2bf(acc[m][nc][3] * a4[3] + s4[3]);
            *(ushort4*)&Hs[srow * 104 + o0] = pk;
        }
    }
    __syncthreads();
    for (int v = t; v < 768; v += 256) {
        int s = v / 12, g = v % 12;
        *(u16x8*)&hbuf[((size_t)b * HWn + hw0 + s) * Cn + g * 8] = *(const u16x8*)&Hs[s * 104 + g * 8];
    }
}

// ---------------- grapher: cat -> fcg+BN+GELU -> fc2+BN+residual -> r (bf16, in-place over h) ----------------
__global__ __launch_bounds__(256) void grapher_kernel(
    const ushort* __restrict__ hbuf, const float* __restrict__ Xres,
    const ushort* __restrict__ wgp, const ushort* __restrict__ w2p,
    const float* __restrict__ prm,
    const float* __restrict__ cmin2, const float* __restrict__ rmin2,
    ushort* __restrict__ rbuf)
{
    __shared__ __align__(16) ushort Xs[64 * 200];
    __shared__ __align__(16) ushort Gs[64 * 200];
    int bid = blockIdx.x, b = bid / TPI, hw0 = (bid % TPI) * NT;
    int t = threadIdx.x, lane = t & 63, wave = t >> 6;
    int wm = wave >> 1, wn = wave & 1, q = lane >> 4, sl = lane & 15;

    for (int v = t; v < 768; v += 256) {
        int s = v / 12, g = v % 12;
        u16x8 hv = *(const u16x8*)&hbuf[((size_t)b * HWn + hw0 + s) * Cn + g * 8];
        *(u16x8*)&Xs[s * 200 + g * 8] = hv;
        int pos = hw0 + s, i = pos / Wn, j = pos - i * Wn;
        const float* cm = &cmin2[(((size_t)b * 112 + j) * 2 + (i & 1)) * 96 + g * 8];
        const float* rm = &rmin2[(((size_t)b * 112 + i) * 2 + (j & 1)) * 96 + g * 8];
        union { u16x8 v; ushort u[8]; } hh, xx;
        hh.v = hv;
        #pragma unroll
        for (int e = 0; e < 8; ++e) {
            float hf = bf2f(hh.u[e]);
            xx.u[e] = f2bf(fmaxf(hf - cm[e], hf - rm[e]));
        }
        *(u16x8*)&Xs[s * 200 + 96 + g * 8] = xx.v;
    }
    __syncthreads();

    // fcg: M=192, K=192
    f32x4 acc[6][2] = {};
    #pragma unroll
    for (int kc = 0; kc < 6; ++kc) {
        bf16x8 b0 = *(const bf16x8*)&Xs[(wn * 32 + sl) * 200 + kc * 32 + q * 8];
        bf16x8 b1 = *(const bf16x8*)&Xs[(wn * 32 + 16 + sl) * 200 + kc * 32 + q * 8];
        #pragma unroll
        for (int m = 0; m < 6; ++m) {
            bf16x8 af = *(const bf16x8*)&wgp[(((wm * 6 + m) * 6 + kc) * 64 + lane) * 8];
            acc[m][0] = MFMA16(af, b0, acc[m][0]);
            acc[m][1] = MFMA16(af, b1, acc[m][1]);
        }
    }
    #pragma unroll
    for (int m = 0; m < 6; ++m) {
        int o0 = (wm * 6 + m) * 16 + q * 4;
        f32x4 a4 = *(const f32x4*)&prm[192 + o0];
        f32x4 s4 = *(const f32x4*)&prm[384 + o0];
        #pragma unroll
        for (int nc = 0; nc < 2; ++nc) {
            int srow = wn * 32 + nc * 16 + sl;
            ushort4 pk;
            pk.x = f2bf(gelu_f(acc[m][nc][0] * a4[0] + s4[0]));
            pk.y = f2bf(gelu_f(acc[m][nc][1] * a4[1] + s4[1]));
            pk.z = f2bf(gelu_f(acc[m][nc][2] * a4[2] + s4[2]));
            pk.w = f2bf(gelu_f(acc[m][nc][3] * a4[3] + s4[3]));
            *(ushort4*)&Gs[srow * 200 + o0] = pk;
        }
    }
    __syncthreads();

    // fc2: M=96, K=192
    f32x4 acc2[3][2] = {};
    #pragma unroll
    for (int kc = 0; kc < 6; ++kc) {
        bf16x8 b0 = *(const bf16x8*)&Gs[(wn * 32 + sl) * 200 + kc * 32 + q * 8];
        bf16x8 b1 = *(const bf16x8*)&Gs[(wn * 32 + 16 + sl) * 200 + kc * 32 + q * 8];
        #pragma unroll
        for (int m = 0; m < 3; ++m) {
            bf16x8 af = *(const bf16x8*)&w2p[(((wm * 3 + m) * 6 + kc) * 64 + lane) * 8];
            acc2[m][0] = MFMA16(af, b0, acc2[m][0]);
            acc2[m][1] = MFMA16(af, b1, acc2[m][1]);
        }
    }
    #pragma unroll
    for (int m = 0; m < 3; ++m) {
        int o0 = (wm * 3 + m) * 16 + q * 4;
        f32x4 a4 = *(const f32x4*)&prm[576 + o0];
        f32x4 s4 = *(const f32x4*)&prm[672 + o0];
        #pragma unroll
        for (int nc = 0; nc < 2; ++nc) {
            int srow = wn * 32 + nc * 16 + sl, sgl = hw0 + srow;
            ushort4 pk;
            float r0 = acc2[m][nc][0] * a4[0] + s4[0] + Xres[((size_t)b * Cn + o0 + 0) * HWn + sgl];
            float r1 = acc2[m][nc][1] * a4[1] + s4[1] + Xres[((size_t)b * Cn + o0 + 1) * HWn + sgl];
            float r2 = acc2[m][nc][2] * a4[2] + s4[2] + Xres[((size_t)b * Cn + o0 + 2) * HWn + sgl];
            float r3 = acc2[m][nc][3] * a4[3] + s4[3] + Xres[((size_t)b * Cn + o0 + 3) * HWn + sgl];
            pk.x = f2bf(r0); pk.y = f2bf(r1); pk.z = f2bf(r2); pk.w = f2bf(r3);
            *(ushort4*)&Xs[srow * 200 + o0] = pk;
        }
    }
    __syncthreads();
    for (int v = t; v < 768; v += 256) {
        int s = v / 12, g = v % 12;
        *(u16x8*)&rbuf[((size_t)b * HWn + hw0 + s) * Cn + g * 8] = *(const u16x8*)&Xs[s * 200 + g * 8];
    }
}

// ---------------- FFN v12: r5 structure + pre-barrier wf2 register prefetch (T14) ----------------
// Chunked (4x96 mid), slab-reused LDS (26.6 KB). NEW: each chunk's 9 wf2p A-frags
// are loaded into registers BEFORE the barrier (latency hides under gelu+barrier),
// so the post-barrier consume phase only waits on ds_reads.
__global__ __launch_bounds__(256) void ffn_kernel(
    const ushort* __restrict__ rbuf,
    const ushort* __restrict__ wf1p, const float* __restrict__ bf1,
    const ushort* __restrict__ wf2p, const float* __restrict__ bf2,
    float* __restrict__ Out)
{
    __shared__ __align__(16) ushort S[2 * 6656];    // 26.6 KB: slab0 | slab1(=Rs)
    ushort* slab0 = S;
    ushort* Rs    = S + 6656;                       // staging + odd-chunk mid
    int bid = blockIdx.x, b = bid / TPI, hw0 = (bid % TPI) * NT;
    int t = threadIdx.x, lane = t & 63, wave = t >> 6;
    int wm = wave >> 1, wn = wave & 1, q = lane >> 4, sl = lane & 15;

    for (int v = t; v < 768; v += 256) {
        int s = v / 12, g = v % 12;
        *(u16x8*)&Rs[s * 104 + g * 8] = *(const u16x8*)&rbuf[((size_t)b * HWn + hw0 + s) * Cn + g * 8];
    }
    __syncthreads();

    bf16x8 rb[3][2];
    #pragma unroll
    for (int kc = 0; kc < 3; ++kc) {
        rb[kc][0] = *(const bf16x8*)&Rs[(wn * 32 + sl) * 104 + kc * 32 + q * 8];
        rb[kc][1] = *(const bf16x8*)&Rs[(wn * 32 + 16 + sl) * 104 + kc * 32 + q * 8];
    }

    f32x4 acc2[3][2] = {};
    #pragma unroll 1
    for (int c = 0; c < 4; ++c) {
        // ffn1 slice: global mt = c*6 + wm*3 + m, K=96 (3 kc)
        f32x4 a1[3][2] = {};
        #pragma unroll
        for (int kc = 0; kc < 3; ++kc)
            #pragma unroll
            for (int m = 0; m < 3; ++m) {
                bf16x8 af = *(const bf16x8*)&wf1p[(((c * 6 + wm * 3 + m) * 3 + kc) * 64 + lane) * 8];
                a1[m][0] = MFMA16(af, rb[kc][0], a1[m][0]);
                a1[m][1] = MFMA16(af, rb[kc][1], a1[m][1]);
            }
        // ---- PREFETCH: this chunk's wf2 A-frags into registers (consumed post-bar) ----
        bf16x8 w2f[3][3];
        #pragma unroll
        for (int kc = 0; kc < 3; ++kc)
            #pragma unroll
            for (int m = 0; m < 3; ++m)
                w2f[kc][m] = *(const bf16x8*)&wf2p[(((wm * 3 + m) * 12 + c * 3 + kc) * 64 + lane) * 8];
        // epilogue: gelu -> chunk slab (loads above drain under this VALU work)
        ushort* mc = (c & 1) ? Rs : slab0;
        #pragma unroll
        for (int m = 0; m < 3; ++m) {
            int ol = (wm * 3 + m) * 16 + q * 4;          // 0..95 within chunk
            f32x4 b4 = *(const f32x4*)&bf1[c * 96 + ol];
            #pragma unroll
            for (int nc = 0; nc < 2; ++nc) {
                int srow = wn * 32 + nc * 16 + sl;
                ushort4 pk;
                pk.x = f2bf(gelu_f(a1[m][nc][0] + b4[0]));
                pk.y = f2bf(gelu_f(a1[m][nc][1] + b4[1]));
                pk.z = f2bf(gelu_f(a1[m][nc][2] + b4[2]));
                pk.w = f2bf(gelu_f(a1[m][nc][3] + b4[3]));
                *(ushort4*)&mc[srow * 104 + ol] = pk;
            }
        }
        __syncthreads();
        // ffn2 partial accumulation: weights already in w2f registers
        #pragma unroll
        for (int kc = 0; kc < 3; ++kc) {
            bf16x8 m0 = *(const bf16x8*)&mc[(wn * 32 + sl) * 104 + kc * 32 + q * 8];
            bf16x8 m1 = *(const bf16x8*)&mc[(wn * 32 + 16 + sl) * 104 + kc * 32 + q * 8];
            acc2[0][0] = MFMA16(w2f[kc][0], m0, acc2[0][0]);
            acc2[0][1] = MFMA16(w2f[kc][0], m1, acc2[0][1]);
            acc2[1][0] = MFMA16(w2f[kc][1], m0, acc2[1][0]);
            acc2[1][1] = MFMA16(w2f[kc][1], m1, acc2[1][1]);
            acc2[2][0] = MFMA16(w2f[kc][2], m0, acc2[2][0]);
            acc2[2][1] = MFMA16(w2f[kc][2], m1, acc2[2][1]);
        }
        // no trailing barrier: next chunk writes the OTHER slab; its barrier
        // orders those writes against this chunk's reads (double-buffer, r5-proven).
    }
    #pragma unroll
    for (int m = 0; m < 3; ++m) {
        int o0 = (wm * 3 + m) * 16 + q * 4;
        f32x4 b4 = *(const f32x4*)&bf2[o0];
        #pragma unroll
        for (int nc = 0; nc < 2; ++nc) {
            int sgl = hw0 + wn * 32 + nc * 16 + sl;
            Out[((size_t)b * Cn + o0 + 0) * HWn + sgl] = acc2[m][nc][0] + b4[0];
            Out[((size_t)b * Cn + o0 + 1) * HWn + sgl] = acc2[m][nc][1] + b4[1];
            Out[((size_t)b * Cn + o0 + 2) * HWn + sgl] = acc2[m][nc][2] + b4[2];
            Out[((size_t)b * Cn + o0 + 3) * HWn + sgl] = acc2[m][nc][3] + b4[3];
        }
    }
}

extern "C" void kernel_launch(void* const* d_in, const int* in_sizes, int n_in,
                              void* d_out, int out_size, void* d_ws, size_t ws_size,
                              hipStream_t stream) {
    (void)in_sizes; (void)n_in; (void)out_size; (void)ws_size;
    const float* x   = (const float*)d_in[0];
    const float* w1  = (const float*)d_in[1];
    const float* b1  = (const float*)d_in[2];
    const float* g1  = (const float*)d_in[3];
    const float* be1 = (const float*)d_in[4];
    const float* m1  = (const float*)d_in[5];
    const float* v1  = (const float*)d_in[6];
    const float* wg  = (const float*)d_in[7];
    const float* bg  = (const float*)d_in[8];
    const float* gg  = (const float*)d_in[9];
    const float* beg = (const float*)d_in[10];
    const float* mg  = (const float*)d_in[11];
    const float* vg  = (const float*)d_in[12];
    const float* w2  = (const float*)d_in[13];
    const float* b2  = (const float*)d_in[14];
    const float* g2  = (const float*)d_in[15];
    const float* be2 = (const float*)d_in[16];
    const float* m2  = (const float*)d_in[17];
    const float* v2  = (const float*)d_in[18];
    const float* wf1 = (const float*)d_in[19];
    const float* bf1 = (const float*)d_in[20];
    const float* wf2 = (const float*)d_in[21];
    const float* bf2 = (const float*)d_in[22];
    float* out = (float*)d_out;

    char* base = (char*)d_ws;
    const size_t H_BYTES   = (size_t)Bn * HWn * Cn * 2;
    const size_t MIN_BYTES = (size_t)Bn * 112 * 2 * 96 * 4;
    ushort* hbuf  = (ushort*)base;                         // h, overwritten by r
    float*  rmin2 = (float*)(base + H_BYTES);
    float*  cmin2 = (float*)(base + H_BYTES + MIN_BYTES);
    float*  prm   = (float*)(base + H_BYTES + 2 * MIN_BYTES);
    ushort* wpack = (ushort*)(base + H_BYTES + 2 * MIN_BYTES + 3072);
    ushort* w1p  = wpack;
    ushort* wgp  = wpack + 9216;
    ushort* w2p  = wpack + 46080;
    ushort* wf1p = wpack + 64512;
    ushort* wf2p = wpack + 101376;

    params_kernel<<<dim3(1), dim3(256), 0, stream>>>(
        b1, g1, be1, m1, v1, bg, gg, beg, mg, vg, b2, g2, be2, m2, v2, prm);
    pack_kernel<<<dim3(540), dim3(256), 0, stream>>>(w1, wg, w2, wf1, wf2, wpack);

    dim3 blk(256);
    fc1_kernel<<<dim3(Bn * TPI), blk, 0, stream>>>(x, w1p, prm, hbuf);
    mins_kernel<<<dim3(Bn * 2 * 112), blk, 0, stream>>>(hbuf, rmin2, cmin2);
    grapher_kernel<<<dim3(Bn * TPI), blk, 0, stream>>>(hbuf, x, wgp, w2p, prm, cmin2, rmin2, hbuf);
    ffn_kernel<<<dim3(Bn * TPI), blk, 0, stream>>>(hbuf, wf1p, bf1, wf2p, bf2, out);
}